// Round 4
// baseline (1059.977 us; speedup 1.0000x reference)
//
#include <hip/hip_runtime.h>
#include <stdint.h>
#include <stddef.h>

// GraphConvolution: out = relu(S @ S @ S @ ((x .* mask / 0.9) @ W))
//   x: [16384,512] f32, S: [16384,16384] f32, W: [512,128] f32, mask: [16384,512] f32
// bf16 MFMA (16x16x32); S converted fp32->bf16 in registers (3 streaming passes of
// 1.07 GB => ~515us HBM floor). Feat transposed bf16 FT[128][16384]. No K-split.
// Pipeline (T3/T4): 4 LDS buffers, DMA issued 2 stages ahead, counted
// s_waitcnt vmcnt(N) + raw s_barrier per stage (NEVER vmcnt(0) in the loop),
// A in 2 ping-pong register sets, loop unrolled x4 => all indices literal.
// Safety: per-wave vmcnt(N) BEFORE barrier drains own stage-s DMA => after
// barrier ALL waves' stage-s DMA landed (RAW). DMA(s+2) writes the buffer last
// read at stage s-2, two barriers back (WAR). Edge-stage counts verified.

#define NROWS 16384
#define KDIN  512
#define NDOUT 128

typedef __attribute__((ext_vector_type(8))) short bf16x8;
typedef __attribute__((ext_vector_type(4))) float f32x4;
typedef __attribute__((ext_vector_type(4))) unsigned short u16x4;

__device__ __forceinline__ unsigned short f2bf(float f) {
  union { float f; unsigned u; } v; v.f = f;
  unsigned r = v.u + 0x7FFFu + ((v.u >> 16) & 1u);   // RNE
  return (unsigned short)(r >> 16);
}

__device__ __forceinline__ void gld_lds16(const void* g, void* l) {
  __builtin_amdgcn_global_load_lds(
      (const __attribute__((address_space(1))) void*)g,
      (__attribute__((address_space(3))) void*)l, 16, 0, 0);
}

__device__ __forceinline__ float4 dmul(float4 a, float4 m) {
  const float s = (float)(1.0 / 0.9);
  float4 r; r.x = a.x*m.x*s; r.y = a.y*m.y*s; r.z = a.z*m.z*s; r.w = a.w*m.w*s;
  return r;
}

// C[32 x 128] = A-rows (f32, optionally .*mask/0.9) @ B, B transposed bf16
// BT[128][ldb]. 256 threads = 4 waves: wave w -> row-group (w&1)*16, n-half (w>>1)*64.
// OUT=0: write bf16 FT[128][16384] (transposed). OUT=1: write relu fp32 out.
template<int DROP, int OUT>
__global__ __launch_bounds__(256, 2)
void gemm32(const float* __restrict__ A, const float* __restrict__ Am,
            const unsigned short* __restrict__ BT,
            int lda, int ldb, int K,
            unsigned short* __restrict__ FT, float* __restrict__ out)
{
  __shared__ unsigned short ldsB[4 * 8192];   // 4 x [128 n][64 k] bf16 = 64 KiB
  const int tid = threadIdx.x;
  const int w = tid >> 6, l = tid & 63;
  const int g = l >> 4, lm = l & 15;
  const int rg = w & 1, nh = w >> 1;
  const int mtile = blockIdx.x;
  const int nst = K >> 6;                     // stages; 8 or 256 (multiple of 4)

  // per-stage vmem ops: 4 DMA + 4 A-loads (+4 mask loads if DROP).
  // WAITN keeps {DMA(s+1), A(s)[, M(s)]} in flight, drains {DMA(s), A(s-1)}.
  constexpr int WAITN = DROP ? 12 : 8;

  const int arow = mtile * 32 + rg * 16 + lm;
  const float* ap = A + (size_t)arow * lda + g * 8;
  const float* mp = DROP ? (Am + (size_t)arow * lda + g * 8) : (const float*)0;

  // B staging: 4 x 16B per thread per stage; source pre-swizzled (chunk c XOR n&7)
  // so LDS stays linear for global_load_lds; read side applies the same XOR.
  const unsigned short* bs[4];
  #pragma unroll
  for (int j = 0; j < 4; ++j) {
    const int n = (tid >> 3) + j * 32, c = tid & 7;
    bs[j] = BT + (size_t)n * ldb + ((c ^ (n & 7)) << 3);
  }

  f32x4 acc[4];
  #pragma unroll
  for (int i = 0; i < 4; ++i) acc[i] = (f32x4){0.f, 0.f, 0.f, 0.f};

  float4 aa[2][4];            // A ping-pong sets (all indices literal after unroll)
  float4 mm[2][4];            // mask sets (dead-stripped when !DROP)

#define ISSUE(S_, BUF_) do {                                                   \
    unsigned short* d_ = ldsB + (BUF_) * 8192 + tid * 8;                       \
    _Pragma("unroll")                                                          \
    for (int j_ = 0; j_ < 4; ++j_)                                             \
      gld_lds16(bs[j_] + (size_t)(S_) * 64, d_ + j_ * 2048);                   \
  } while (0)

#define LOADA(S_, ST_) do {                                                    \
    const float* p_ = ap + (size_t)(S_) * 64;                                  \
    aa[ST_][0] = *(const float4*)(p_);      aa[ST_][1] = *(const float4*)(p_ + 4);  \
    aa[ST_][2] = *(const float4*)(p_ + 32); aa[ST_][3] = *(const float4*)(p_ + 36); \
    if (DROP) {                                                                \
      const float* q_ = mp + (size_t)(S_) * 64;                                \
      mm[ST_][0] = *(const float4*)(q_);      mm[ST_][1] = *(const float4*)(q_ + 4);  \
      mm[ST_][2] = *(const float4*)(q_ + 32); mm[ST_][3] = *(const float4*)(q_ + 36); \
    }                                                                          \
  } while (0)

#define COMPUTE(BUF_, ST_) do {                                                \
    const char* lb_ = (const char*)ldsB + (BUF_) * 16384;                      \
    _Pragma("unroll")                                                          \
    for (int kk = 0; kk < 2; ++kk) {                                           \
      float4 u_ = aa[ST_][kk * 2], v_ = aa[ST_][kk * 2 + 1];                   \
      if (DROP) { u_ = dmul(u_, mm[ST_][kk * 2]); v_ = dmul(v_, mm[ST_][kk * 2 + 1]); } \
      bf16x8 af_;                                                              \
      af_[0] = (short)f2bf(u_.x); af_[1] = (short)f2bf(u_.y);                  \
      af_[2] = (short)f2bf(u_.z); af_[3] = (short)f2bf(u_.w);                  \
      af_[4] = (short)f2bf(v_.x); af_[5] = (short)f2bf(v_.y);                  \
      af_[6] = (short)f2bf(v_.z); af_[7] = (short)f2bf(v_.w);                  \
      _Pragma("unroll")                                                        \
      for (int nt = 0; nt < 4; ++nt) {                                         \
        const int n_ = nh * 64 + nt * 16 + lm;                                 \
        const int off_ = n_ * 128 + (((kk << 6) + (g << 4)) ^ ((n_ & 7) << 4)); \
        bf16x8 bf_ = *(const bf16x8*)(lb_ + off_);                             \
        acc[nt] = __builtin_amdgcn_mfma_f32_16x16x32_bf16(af_, bf_, acc[nt], 0, 0, 0); \
      }                                                                        \
    }                                                                          \
  } while (0)

#define STAGE(S_, BUF_, USE_, LD_) do {                                        \
    asm volatile("s_waitcnt vmcnt(%0)" :: "i"(WAITN) : "memory");              \
    __builtin_amdgcn_s_barrier();                                              \
    __builtin_amdgcn_sched_barrier(0);                                         \
    const int sS_ = (S_);                                                      \
    if (sS_ + 2 < nst) ISSUE(sS_ + 2, ((BUF_) + 2) & 3);                       \
    if (sS_ + 1 < nst) LOADA(sS_ + 1, LD_);                                    \
    COMPUTE(BUF_, USE_);                                                       \
  } while (0)

  // prologue: two DMA stages + A(0) in flight
  ISSUE(0, 0);
  ISSUE(1, 1);
  LOADA(0, 0);

  for (int s0 = 0; s0 < nst; s0 += 4) {
    STAGE(s0 + 0, 0, 0, 1);
    STAGE(s0 + 1, 1, 1, 0);
    STAGE(s0 + 2, 2, 0, 1);
    STAGE(s0 + 3, 3, 1, 0);
  }

#undef STAGE
#undef COMPUTE
#undef LOADA
#undef ISSUE

  // C frag layout: col = lane&15 (= lm), row = (lane>>4)*4 + r (= g*4+r)
  if (OUT == 0) {
    const int m0 = mtile * 32 + rg * 16 + g * 4;
    #pragma unroll
    for (int nt = 0; nt < 4; ++nt) {
      const int n = nh * 64 + nt * 16 + lm;
      u16x4 vv;
      vv[0] = f2bf(acc[nt][0]); vv[1] = f2bf(acc[nt][1]);
      vv[2] = f2bf(acc[nt][2]); vv[3] = f2bf(acc[nt][3]);
      *(u16x4*)(FT + (size_t)n * NROWS + m0) = vv;
    }
  } else {
    float* po = out + ((size_t)mtile * 32 + rg * 16) * NDOUT;
    #pragma unroll
    for (int nt = 0; nt < 4; ++nt) {
      #pragma unroll
      for (int r = 0; r < 4; ++r) {
        po[(g * 4 + r) * NDOUT + nh * 64 + nt * 16 + lm] = fmaxf(acc[nt][r], 0.f);
      }
    }
  }
}

// W [512][128] f32 -> WT [128][512] bf16
__global__ void wconv(const float* __restrict__ W, unsigned short* __restrict__ WT)
{
  const int t = blockIdx.x * 256 + threadIdx.x;   // 65536
  const int n = t & 127, k = t >> 7;
  WT[(size_t)n * KDIN + k] = f2bf(W[(size_t)k * NDOUT + n]);
}

extern "C" void kernel_launch(void* const* d_in, const int* in_sizes, int n_in,
                              void* d_out, int out_size, void* d_ws, size_t ws_size,
                              hipStream_t stream)
{
  const float* x       = (const float*)d_in[0];
  const float* support = (const float*)d_in[1];
  const float* weight  = (const float*)d_in[2];
  const float* dmask   = (const float*)d_in[3];
  float* out = (float*)d_out;
  char* ws = (char*)d_ws;

  // ws layout: FTa 4MiB | FTb 4MiB | WT 128KiB  (= 8.125 MiB used)
  unsigned short* FTa = (unsigned short*)(ws);
  unsigned short* FTb = (unsigned short*)(ws + (size_t)(4 << 20));
  unsigned short* WT  = (unsigned short*)(ws + (size_t)(8 << 20));

  // 1. W -> WT (transposed bf16)
  wconv<<<256, 256, 0, stream>>>(weight, WT);
  // 2. pre_sup = (x .* mask / 0.9) @ W  -> FTa (bf16, transposed)
  gemm32<1, 0><<<512, 256, 0, stream>>>(x, dmask, WT, KDIN, KDIN, KDIN, FTa, (float*)0);
  // 3. three diffusion steps: feat <- S @ feat (full-K, no split)
  gemm32<0, 0><<<512, 256, 0, stream>>>(support, (const float*)0, FTa, NROWS, NROWS, NROWS, FTb, (float*)0);
  gemm32<0, 0><<<512, 256, 0, stream>>>(support, (const float*)0, FTb, NROWS, NROWS, NROWS, FTa, (float*)0);
  // 4. last step fused with relu -> d_out fp32
  gemm32<0, 1><<<512, 256, 0, stream>>>(support, (const float*)0, FTa, NROWS, NROWS, NROWS, (unsigned short*)0, out);
  (void)in_sizes; (void)n_in; (void)out_size; (void)ws_size;
}